// Round 2
// baseline (728.957 us; speedup 1.0000x reference)
//
#include <hip/hip_runtime.h>

#define HD 64
#define SLOPE 0.01f

// ---------------------------------------------------------------------------
// CSR build: count degrees, exclusive-scan to rowptr, fill column indices.
// ---------------------------------------------------------------------------

__global__ __launch_bounds__(256) void count_kernel(const int* __restrict__ ei,
                                                    int* __restrict__ deg, int E) {
    int e = blockIdx.x * blockDim.x + threadIdx.x;
    if (e < E) atomicAdd(&deg[ei[E + e]], 1);   // row 1 = dst
}

// Single-block 1024-thread exclusive scan over deg[0..n) -> rowptr[0..n],
// also emits inv_deg = 1/max(deg,1).
__global__ __launch_bounds__(1024) void scan_kernel(const int* __restrict__ deg,
                                                    int* __restrict__ rowptr,
                                                    float* __restrict__ inv_deg,
                                                    int n) {
    __shared__ int wsum[16];
    __shared__ int s_carry;
    const int tid = threadIdx.x;
    const int lane = tid & 63;
    const int wid = tid >> 6;
    if (tid == 0) s_carry = 0;
    __syncthreads();
    for (int base = 0; base < n; base += 1024) {
        int i = base + tid;
        int v = (i < n) ? deg[i] : 0;
        int x = v;
        #pragma unroll
        for (int d = 1; d < 64; d <<= 1) {
            int y = __shfl_up(x, d, 64);
            if (lane >= d) x += y;
        }
        if (lane == 63) wsum[wid] = x;
        __syncthreads();                    // (A) wave totals ready
        if (wid == 0) {
            int ws = (lane < 16) ? wsum[lane] : 0;
            int xs = ws;
            #pragma unroll
            for (int d = 1; d < 16; d <<= 1) {
                int y = __shfl_up(xs, d, 64);
                if (lane >= d) xs += y;
            }
            if (lane < 16) wsum[lane] = xs - ws;   // exclusive wave prefix
        }
        __syncthreads();                    // (B) exclusive prefixes ready
        int carry = s_carry;
        if (i < n) {
            rowptr[i] = carry + wsum[wid] + (x - v);
            inv_deg[i] = 1.0f / (float)((v > 1) ? v : 1);
        }
        __syncthreads();                    // (C) all readers done with s_carry
        if (tid == 1023) s_carry = carry + wsum[15] + x;  // block total
        __syncthreads();
    }
    if (tid == 0) rowptr[n] = s_carry;
}

__global__ __launch_bounds__(256) void fill_kernel(const int* __restrict__ ei,
                                                   const int* __restrict__ rowptr,
                                                   int* __restrict__ cursor,
                                                   int* __restrict__ colidx, int E) {
    int e = blockIdx.x * blockDim.x + threadIdx.x;
    if (e < E) {
        int src = ei[e];
        int dst = ei[E + e];
        int pos = atomicAdd(&cursor[dst], 1);
        colidx[rowptr[dst] + pos] = src;
    }
}

// ---------------------------------------------------------------------------
// Aggregation: wave-per-node mean over neighbors. Lane layout: s = lane>>4
// (neighbor slot 0..3), c4 = lane&15 (float4 chunk of the 64-ch row). Each
// iteration a wave pulls 4 neighbor rows (4 x 16 lanes x 16B). Low VGPR ->
// full occupancy; this kernel's job is to keep many gathers in flight.
// ---------------------------------------------------------------------------

__global__ __launch_bounds__(256) void aggregate_kernel(
    const float* __restrict__ h_in,       // [N,64]
    float* __restrict__ mean_out,         // [N,64]
    const int* __restrict__ rowptr,
    const int* __restrict__ colidx,
    const float* __restrict__ inv_deg,
    int n) {
    const int lane = threadIdx.x & 63;
    const int wslot = threadIdx.x >> 6;
    const int s = lane >> 4;     // neighbor slot
    const int c4 = lane & 15;    // float4 chunk
    const float4* __restrict__ h4 = (const float4*)h_in;
    float4* __restrict__ m4 = (float4*)mean_out;

    const int wave = blockIdx.x * 4 + wslot;
    const int nwaves = gridDim.x * 4;

    for (int node = wave; node < n; node += nwaves) {
        const int beg = rowptr[node];
        const int end = rowptr[node + 1];
        float4 a0 = {0.f, 0.f, 0.f, 0.f};
        float4 a1 = {0.f, 0.f, 0.f, 0.f};
        int k = beg + s;
        for (; k + 4 < end; k += 8) {       // 2 independent gathers in flight
            int cA = colidx[k];
            int cB = colidx[k + 4];
            float4 vA = h4[(size_t)cA * 16 + c4];
            float4 vB = h4[(size_t)cB * 16 + c4];
            a0.x += vA.x; a0.y += vA.y; a0.z += vA.z; a0.w += vA.w;
            a1.x += vB.x; a1.y += vB.y; a1.z += vB.z; a1.w += vB.w;
        }
        if (k < end) {
            int cA = colidx[k];
            float4 vA = h4[(size_t)cA * 16 + c4];
            a0.x += vA.x; a0.y += vA.y; a0.z += vA.z; a0.w += vA.w;
        }
        a0.x += a1.x; a0.y += a1.y; a0.z += a1.z; a0.w += a1.w;

        // reduce the 4 neighbor slots: butterfly over lane bits 4,5
        #pragma unroll
        for (int d = 16; d <= 32; d <<= 1) {
            a0.x += __shfl_xor(a0.x, d, 64);
            a0.y += __shfl_xor(a0.y, d, 64);
            a0.z += __shfl_xor(a0.z, d, 64);
            a0.w += __shfl_xor(a0.w, d, 64);
        }
        if (s == 0) {
            float id = inv_deg[node];
            float4 m = {a0.x * id, a0.y * id, a0.z * id, a0.w * id};
            m4[(size_t)node * 16 + c4] = m;
        }
    }
}

// ---------------------------------------------------------------------------
// Dense part: out = leaky(mean @ Wl + bl + self @ Wr). 64-node tile per
// block; mean/self tiles staged in LDS (32 KB); lane j holds W[:,j] in
// registers (128 VGPRs), reused across all 16 rows the wave handles.
// ---------------------------------------------------------------------------

__global__ __launch_bounds__(256, 2) void sage_gemm(
    const float* __restrict__ mean,       // [N,64]
    const float* __restrict__ h_in,       // [N,64] (self)
    float* __restrict__ h_out,            // [N,64]
    const float* __restrict__ Wl,         // [64,64] row-major
    const float* __restrict__ bl,         // [64]
    const float* __restrict__ Wr,         // [64,64]
    int n) {
    __shared__ float4 sm[64 * 16];
    __shared__ float4 ss[64 * 16];
    const int lane = threadIdx.x & 63;
    const int wslot = threadIdx.x >> 6;

    float wl[HD], wr[HD];
    #pragma unroll
    for (int c = 0; c < HD; ++c) {
        wl[c] = Wl[c * HD + lane];
        wr[c] = Wr[c * HD + lane];
    }
    const float bias = bl[lane];

    const int base = blockIdx.x * 64;
    const int rows = min(64, n - base);
    const float4* __restrict__ m4 = (const float4*)mean;
    const float4* __restrict__ h4 = (const float4*)h_in;

    for (int i = threadIdx.x; i < rows * 16; i += 256) {
        sm[i] = m4[(size_t)base * 16 + i];
        ss[i] = h4[(size_t)base * 16 + i];
    }
    __syncthreads();

    for (int r = wslot; r < rows; r += 4) {
        float acc = bias;
        #pragma unroll
        for (int c4 = 0; c4 < 16; ++c4) {
            float4 m = sm[r * 16 + c4];
            float4 f = ss[r * 16 + c4];
            acc += m.x * wl[4 * c4 + 0] + m.y * wl[4 * c4 + 1]
                 + m.z * wl[4 * c4 + 2] + m.w * wl[4 * c4 + 3];
            acc += f.x * wr[4 * c4 + 0] + f.y * wr[4 * c4 + 1]
                 + f.z * wr[4 * c4 + 2] + f.w * wr[4 * c4 + 3];
        }
        acc = (acc > 0.0f) ? acc : SLOPE * acc;
        h_out[(size_t)(base + r) * HD + lane] = acc;
    }
}

// ---------------------------------------------------------------------------
// Output projection: out[node] = h[node,:] . Wout + bout  (wave-per-node).
// ---------------------------------------------------------------------------

__global__ __launch_bounds__(256) void out_kernel(const float* __restrict__ h,
                                                  const float* __restrict__ Wout,
                                                  const float* __restrict__ bout,
                                                  float* __restrict__ out, int n) {
    int gtid = blockIdx.x * blockDim.x + threadIdx.x;
    int node = gtid >> 6;
    int lane = gtid & 63;
    if (node >= n) return;
    float v = h[node * HD + lane] * Wout[lane];
    #pragma unroll
    for (int d = 32; d > 0; d >>= 1) v += __shfl_down(v, d, 64);
    if (lane == 0) out[node] = v + bout[0];
}

// ---------------------------------------------------------------------------

extern "C" void kernel_launch(void* const* d_in, const int* in_sizes, int n_in,
                              void* d_out, int out_size, void* d_ws, size_t ws_size,
                              hipStream_t stream) {
    const float* x   = (const float*)d_in[0];
    const int* ei    = (const int*)d_in[1];
    const float* Wl1 = (const float*)d_in[2];
    const float* bl1 = (const float*)d_in[3];
    const float* Wr1 = (const float*)d_in[4];
    const float* Wl2 = (const float*)d_in[5];
    const float* bl2 = (const float*)d_in[6];
    const float* Wr2 = (const float*)d_in[7];
    const float* Wl3 = (const float*)d_in[8];
    const float* bl3 = (const float*)d_in[9];
    const float* Wr3 = (const float*)d_in[10];
    const float* Wout = (const float*)d_in[11];
    const float* bout = (const float*)d_in[12];
    float* out = (float*)d_out;

    const int N = in_sizes[0] / HD;       // 50000
    const int E = in_sizes[1] / 2;        // 800000

    // Workspace layout — float4-accessed buffers first (16B alignment).
    float* hMean  = (float*)d_ws;                   // [N*64]
    float* hA     = hMean + (size_t)N * HD;         // [N*64]
    float* hB     = hA + (size_t)N * HD;            // [N*64]
    int* deg      = (int*)(hB + (size_t)N * HD);    // [N]
    int* cursor   = deg + N;                        // [N]
    int* rowptr   = cursor + N;                     // [N+1]
    float* invdeg = (float*)(rowptr + N + 1);       // [N]
    int* colidx   = (int*)(invdeg + N);             // [E]

    // Zero deg + cursor (contiguous)
    hipMemsetAsync(deg, 0, (size_t)2 * N * sizeof(int), stream);

    const int eb = (E + 255) / 256;
    count_kernel<<<eb, 256, 0, stream>>>(ei, deg, E);
    scan_kernel<<<1, 1024, 0, stream>>>(deg, rowptr, invdeg, N);
    fill_kernel<<<eb, 256, 0, stream>>>(ei, rowptr, cursor, colidx, E);

    const int agrid = 2048;                 // 8192 waves, grid-stride
    const int ggrid = (N + 63) / 64;        // 782 tiles

    aggregate_kernel<<<agrid, 256, 0, stream>>>(x, hMean, rowptr, colidx, invdeg, N);
    sage_gemm<<<ggrid, 256, 0, stream>>>(hMean, x, hA, Wl1, bl1, Wr1, N);

    aggregate_kernel<<<agrid, 256, 0, stream>>>(hA, hMean, rowptr, colidx, invdeg, N);
    sage_gemm<<<ggrid, 256, 0, stream>>>(hMean, hA, hB, Wl2, bl2, Wr2, N);

    aggregate_kernel<<<agrid, 256, 0, stream>>>(hB, hMean, rowptr, colidx, invdeg, N);
    sage_gemm<<<ggrid, 256, 0, stream>>>(hMean, hB, hA, Wl3, bl3, Wr3, N);

    const int ob = (N * HD + 255) / 256;
    out_kernel<<<ob, 256, 0, stream>>>(hA, Wout, bout, out, N);
}

// Round 4
// 325.806 us; speedup vs baseline: 2.2374x; 2.2374x over previous
//
#include <hip/hip_runtime.h>

#define HD 64
#define SLOPE 0.01f

// ---------------------------------------------------------------------------
// CSR build: count -> 3-phase scan -> fill.
// ---------------------------------------------------------------------------

__global__ __launch_bounds__(256) void count_kernel(const int* __restrict__ ei,
                                                    int* __restrict__ deg, int E) {
    int e = blockIdx.x * blockDim.x + threadIdx.x;
    if (e < E) atomicAdd(&deg[ei[E + e]], 1);   // row 1 = dst
}

// Phase 1: block-local exclusive scan of deg -> rowptr, block totals -> bsum,
// and inv_deg = 1/max(deg,1).
__global__ __launch_bounds__(256) void scan_p1(const int* __restrict__ deg,
                                               int* __restrict__ rowptr,
                                               float* __restrict__ invdeg,
                                               int* __restrict__ bsum, int n) {
    __shared__ int wsum[4];
    const int t = threadIdx.x, lane = t & 63, wid = t >> 6;
    const int i = blockIdx.x * 256 + t;
    int v = (i < n) ? deg[i] : 0;
    int x = v;
    #pragma unroll
    for (int d = 1; d < 64; d <<= 1) { int y = __shfl_up(x, d, 64); if (lane >= d) x += y; }
    if (lane == 63) wsum[wid] = x;
    __syncthreads();
    if (wid == 0 && lane < 4) {
        int ws = wsum[lane], xs = ws;
        #pragma unroll
        for (int d = 1; d < 4; d <<= 1) { int y = __shfl_up(xs, d, 64); if (lane >= d) xs += y; }
        wsum[lane] = xs - ws;
    }
    __syncthreads();
    int excl = wsum[wid] + (x - v);
    if (i < n) {
        rowptr[i] = excl;
        invdeg[i] = 1.0f / (float)((v > 1) ? v : 1);
    }
    if (t == 255) bsum[blockIdx.x] = excl + v;
}

// Phase 2: exclusive scan of bsum[nb] in place (nb <= 256), one block.
__global__ __launch_bounds__(256) void scan_p2(int* __restrict__ bsum, int nb) {
    __shared__ int wsum[4];
    const int t = threadIdx.x, lane = t & 63, wid = t >> 6;
    int v = (t < nb) ? bsum[t] : 0;
    int x = v;
    #pragma unroll
    for (int d = 1; d < 64; d <<= 1) { int y = __shfl_up(x, d, 64); if (lane >= d) x += y; }
    if (lane == 63) wsum[wid] = x;
    __syncthreads();
    if (wid == 0 && lane < 4) {
        int ws = wsum[lane], xs = ws;
        #pragma unroll
        for (int d = 1; d < 4; d <<= 1) { int y = __shfl_up(xs, d, 64); if (lane >= d) xs += y; }
        wsum[lane] = xs - ws;
    }
    __syncthreads();
    if (t < nb) bsum[t] = wsum[wid] + (x - v);
}

// Phase 3: add block offsets; write rowptr[n] = E.
__global__ __launch_bounds__(256) void scan_p3(int* __restrict__ rowptr,
                                               const int* __restrict__ bsum,
                                               int n, int E) {
    int i = blockIdx.x * 256 + threadIdx.x;
    if (i < n) rowptr[i] += bsum[blockIdx.x];
    if (i == 0) rowptr[n] = E;
}

__global__ __launch_bounds__(256) void fill_kernel(const int* __restrict__ ei,
                                                   const int* __restrict__ rowptr,
                                                   int* __restrict__ cursor,
                                                   int* __restrict__ colidx, int E) {
    int e = blockIdx.x * blockDim.x + threadIdx.x;
    if (e < E) {
        int src = ei[e];
        int dst = ei[E + e];
        int pos = atomicAdd(&cursor[dst], 1);
        colidx[rowptr[dst] + pos] = src;
    }
}

// ---------------------------------------------------------------------------
// Aggregation: wave-per-node mean. Lane = (s = neighbor slot 0..3, c4 = f4
// chunk 0..15). colidx prefetched with ONE coalesced 64-wide load, then
// distributed by __shfl. NOTE: every __shfl is executed by ALL 64 lanes
// (ds_bpermute sources from inactive lanes are undefined — R3's bug was a
// shfl inside the divergent remainder branch).
// ---------------------------------------------------------------------------

__global__ __launch_bounds__(256) void aggregate_kernel(
    const float* __restrict__ h_in, float* __restrict__ mean_out,
    const int* __restrict__ rowptr, const int* __restrict__ colidx,
    const float* __restrict__ inv_deg, int n) {
    const int lane = threadIdx.x & 63;
    const int wslot = threadIdx.x >> 6;
    const int s = lane >> 4;
    const int c4 = lane & 15;
    const float4* __restrict__ h4 = (const float4*)h_in;
    float4* __restrict__ m4 = (float4*)mean_out;

    const int wave = blockIdx.x * 4 + wslot;
    const int nwaves = gridDim.x * 4;

    for (int node = wave; node < n; node += nwaves) {
        const int beg = rowptr[node];
        const int end = rowptr[node + 1];
        float4 a = {0.f, 0.f, 0.f, 0.f};
        int k = beg;
        while (k < end) {
            int m = end - k; if (m > 64) m = 64;
            int ci = 0;
            if (lane < m) ci = colidx[k + lane];
            const int full = m >> 2;
            #pragma unroll 4
            for (int t = 0; t < full; ++t) {
                int idx = __shfl(ci, 4 * t + s, 64);   // all lanes active
                float4 v = h4[(size_t)idx * 16 + c4];
                a.x += v.x; a.y += v.y; a.z += v.z; a.w += v.w;
            }
            const int rem = m & 3;
            // shfl OUTSIDE the divergent branch; value dead in masked lanes.
            int idxr = __shfl(ci, (4 * full + s) & 63, 64);
            if (s < rem) {
                float4 v = h4[(size_t)idxr * 16 + c4];
                a.x += v.x; a.y += v.y; a.z += v.z; a.w += v.w;
            }
            k += m;
        }
        // reduce 4 neighbor slots (lane bits 4,5)
        #pragma unroll
        for (int d = 16; d <= 32; d <<= 1) {
            a.x += __shfl_xor(a.x, d, 64);
            a.y += __shfl_xor(a.y, d, 64);
            a.z += __shfl_xor(a.z, d, 64);
            a.w += __shfl_xor(a.w, d, 64);
        }
        if (s == 0) {
            float id = inv_deg[node];
            float4 mm = {a.x * id, a.y * id, a.z * id, a.w * id};
            m4[(size_t)node * 16 + c4] = mm;
        }
    }
}

// ---------------------------------------------------------------------------
// Dense: out = leaky(mean @ Wl + bl + self @ Wr), 64x64 tile per block,
// 4x4 register blocking per thread (rows r0+16s, cols j0..j0+3). All frags
// constant-indexed float4 -> stays in registers (no R2-style spill).
// A-tiles at stride 68 floats: reads hit 2 addrs/bank = conflict-free.
// ---------------------------------------------------------------------------

#define FMA4(acc, am, b0, b1, b2, b3)                                  \
    acc.x += am.x * b0.x + am.y * b1.x + am.z * b2.x + am.w * b3.x;    \
    acc.y += am.x * b0.y + am.y * b1.y + am.z * b2.y + am.w * b3.y;    \
    acc.z += am.x * b0.z + am.y * b1.z + am.z * b2.z + am.w * b3.z;    \
    acc.w += am.x * b0.w + am.y * b1.w + am.z * b2.w + am.w * b3.w;

__global__ __launch_bounds__(256, 2) void sage_gemm(
    const float* __restrict__ mean, const float* __restrict__ h_in,
    float* __restrict__ h_out,
    const float* __restrict__ Wl, const float* __restrict__ bl,
    const float* __restrict__ Wr, int n) {
    __shared__ float sA[64 * 68];    // mean tile (stride 68)
    __shared__ float sS[64 * 68];    // self tile (stride 68)
    __shared__ float sWl[64 * 64];
    __shared__ float sWr[64 * 64];
    const int t = threadIdx.x;
    const int r0 = t & 15;
    const int j0 = (t >> 4) * 4;
    const int base = blockIdx.x * 64;
    const int rows = min(64, n - base);
    const float4* __restrict__ m4 = (const float4*)mean;
    const float4* __restrict__ h4 = (const float4*)h_in;

    #pragma unroll
    for (int idx = 0; idx < 4; ++idx) {               // W: 1024 f4 / 256 thr
        int i = t + idx * 256;
        ((float4*)sWl)[i] = ((const float4*)Wl)[i];
        ((float4*)sWr)[i] = ((const float4*)Wr)[i];
    }
    #pragma unroll
    for (int idx = 0; idx < 4; ++idx) {               // A/self tiles
        int i = t + idx * 256;
        int r = i >> 4, c4 = i & 15;
        float4 va = {0.f, 0.f, 0.f, 0.f}, vs = {0.f, 0.f, 0.f, 0.f};
        if (r < rows) {
            va = m4[(size_t)(base + r) * 16 + c4];
            vs = h4[(size_t)(base + r) * 16 + c4];
        }
        *(float4*)(sA + r * 68 + 4 * c4) = va;
        *(float4*)(sS + r * 68 + 4 * c4) = vs;
    }
    __syncthreads();

    const float4 bias = *(const float4*)(bl + j0);
    float4 acc0 = bias, acc1 = bias, acc2 = bias, acc3 = bias;

    #pragma unroll 2
    for (int k4 = 0; k4 < 16; ++k4) {
        // mean part
        float4 b0 = *(const float4*)(sWl + (4 * k4 + 0) * 64 + j0);
        float4 b1 = *(const float4*)(sWl + (4 * k4 + 1) * 64 + j0);
        float4 b2 = *(const float4*)(sWl + (4 * k4 + 2) * 64 + j0);
        float4 b3 = *(const float4*)(sWl + (4 * k4 + 3) * 64 + j0);
        float4 a0 = *(const float4*)(sA + (r0 +  0) * 68 + 4 * k4);
        float4 a1 = *(const float4*)(sA + (r0 + 16) * 68 + 4 * k4);
        float4 a2 = *(const float4*)(sA + (r0 + 32) * 68 + 4 * k4);
        float4 a3 = *(const float4*)(sA + (r0 + 48) * 68 + 4 * k4);
        FMA4(acc0, a0, b0, b1, b2, b3)
        FMA4(acc1, a1, b0, b1, b2, b3)
        FMA4(acc2, a2, b0, b1, b2, b3)
        FMA4(acc3, a3, b0, b1, b2, b3)
        // self part
        b0 = *(const float4*)(sWr + (4 * k4 + 0) * 64 + j0);
        b1 = *(const float4*)(sWr + (4 * k4 + 1) * 64 + j0);
        b2 = *(const float4*)(sWr + (4 * k4 + 2) * 64 + j0);
        b3 = *(const float4*)(sWr + (4 * k4 + 3) * 64 + j0);
        a0 = *(const float4*)(sS + (r0 +  0) * 68 + 4 * k4);
        a1 = *(const float4*)(sS + (r0 + 16) * 68 + 4 * k4);
        a2 = *(const float4*)(sS + (r0 + 32) * 68 + 4 * k4);
        a3 = *(const float4*)(sS + (r0 + 48) * 68 + 4 * k4);
        FMA4(acc0, a0, b0, b1, b2, b3)
        FMA4(acc1, a1, b0, b1, b2, b3)
        FMA4(acc2, a2, b0, b1, b2, b3)
        FMA4(acc3, a3, b0, b1, b2, b3)
    }

    #define STORE_ROW(S, ACC)                                               \
        { int r = r0 + 16 * S;                                              \
          if (r < rows) {                                                   \
              float4 o;                                                     \
              o.x = (ACC.x > 0.f) ? ACC.x : SLOPE * ACC.x;                  \
              o.y = (ACC.y > 0.f) ? ACC.y : SLOPE * ACC.y;                  \
              o.z = (ACC.z > 0.f) ? ACC.z : SLOPE * ACC.z;                  \
              o.w = (ACC.w > 0.f) ? ACC.w : SLOPE * ACC.w;                  \
              *(float4*)(h_out + (size_t)(base + r) * HD + j0) = o;         \
          } }
    STORE_ROW(0, acc0)
    STORE_ROW(1, acc1)
    STORE_ROW(2, acc2)
    STORE_ROW(3, acc3)
    #undef STORE_ROW
}

// ---------------------------------------------------------------------------
// Output projection: out[node] = h[node,:] . Wout + bout  (wave-per-node).
// ---------------------------------------------------------------------------

__global__ __launch_bounds__(256) void out_kernel(const float* __restrict__ h,
                                                  const float* __restrict__ Wout,
                                                  const float* __restrict__ bout,
                                                  float* __restrict__ out, int n) {
    int gtid = blockIdx.x * blockDim.x + threadIdx.x;
    int node = gtid >> 6;
    int lane = gtid & 63;
    if (node >= n) return;
    float v = h[node * HD + lane] * Wout[lane];
    #pragma unroll
    for (int d = 32; d > 0; d >>= 1) v += __shfl_down(v, d, 64);
    if (lane == 0) out[node] = v + bout[0];
}

// ---------------------------------------------------------------------------

extern "C" void kernel_launch(void* const* d_in, const int* in_sizes, int n_in,
                              void* d_out, int out_size, void* d_ws, size_t ws_size,
                              hipStream_t stream) {
    const float* x   = (const float*)d_in[0];
    const int* ei    = (const int*)d_in[1];
    const float* Wl1 = (const float*)d_in[2];
    const float* bl1 = (const float*)d_in[3];
    const float* Wr1 = (const float*)d_in[4];
    const float* Wl2 = (const float*)d_in[5];
    const float* bl2 = (const float*)d_in[6];
    const float* Wr2 = (const float*)d_in[7];
    const float* Wl3 = (const float*)d_in[8];
    const float* bl3 = (const float*)d_in[9];
    const float* Wr3 = (const float*)d_in[10];
    const float* Wout = (const float*)d_in[11];
    const float* bout = (const float*)d_in[12];
    float* out = (float*)d_out;

    const int N = in_sizes[0] / HD;       // 50000
    const int E = in_sizes[1] / 2;        // 800000

    // Workspace layout — float4-accessed buffers first (16B alignment).
    float* hMean  = (float*)d_ws;                   // [N*64]
    float* hA     = hMean + (size_t)N * HD;         // [N*64]
    float* hB     = hA + (size_t)N * HD;            // [N*64]
    int* deg      = (int*)(hB + (size_t)N * HD);    // [N]
    int* cursor   = deg + N;                        // [N]
    int* rowptr   = cursor + N;                     // [N+1]
    float* invdeg = (float*)(rowptr + N + 1);       // [N]
    int* colidx   = (int*)(invdeg + N);             // [E]
    int* bsum     = colidx + E;                     // [<=256]

    hipMemsetAsync(deg, 0, (size_t)2 * N * sizeof(int), stream);

    const int eb = (E + 255) / 256;
    const int nb = (N + 255) / 256;       // 196 <= 256
    count_kernel<<<eb, 256, 0, stream>>>(ei, deg, E);
    scan_p1<<<nb, 256, 0, stream>>>(deg, rowptr, invdeg, bsum, N);
    scan_p2<<<1, 256, 0, stream>>>(bsum, nb);
    scan_p3<<<nb, 256, 0, stream>>>(rowptr, bsum, N, E);
    fill_kernel<<<eb, 256, 0, stream>>>(ei, rowptr, cursor, colidx, E);

    const int agrid = 2048;               // 8192 waves, grid-stride
    const int ggrid = (N + 63) / 64;      // 782 tiles

    aggregate_kernel<<<agrid, 256, 0, stream>>>(x, hMean, rowptr, colidx, invdeg, N);
    sage_gemm<<<ggrid, 256, 0, stream>>>(hMean, x, hA, Wl1, bl1, Wr1, N);

    aggregate_kernel<<<agrid, 256, 0, stream>>>(hA, hMean, rowptr, colidx, invdeg, N);
    sage_gemm<<<ggrid, 256, 0, stream>>>(hMean, hA, hB, Wl2, bl2, Wr2, N);

    aggregate_kernel<<<agrid, 256, 0, stream>>>(hB, hMean, rowptr, colidx, invdeg, N);
    sage_gemm<<<ggrid, 256, 0, stream>>>(hMean, hB, hA, Wl3, bl3, Wr3, N);

    const int ob = (N * HD + 255) / 256;
    out_kernel<<<ob, 256, 0, stream>>>(hA, Wout, bout, out, N);
}

// Round 5
// 321.258 us; speedup vs baseline: 2.2691x; 1.0142x over previous
//
#include <hip/hip_runtime.h>

#define HD 64
#define SLOPE 0.01f

// ---------------------------------------------------------------------------
// CSR build: count -> 3-phase scan -> fill.
// ---------------------------------------------------------------------------

__global__ __launch_bounds__(256) void count_kernel(const int* __restrict__ ei,
                                                    int* __restrict__ deg, int E) {
    int e = blockIdx.x * blockDim.x + threadIdx.x;
    if (e < E) atomicAdd(&deg[ei[E + e]], 1);   // row 1 = dst
}

// Phase 1: block-local exclusive scan of deg -> rowptr, block totals -> bsum,
// and inv_deg = 1/max(deg,1).
__global__ __launch_bounds__(256) void scan_p1(const int* __restrict__ deg,
                                               int* __restrict__ rowptr,
                                               float* __restrict__ invdeg,
                                               int* __restrict__ bsum, int n) {
    __shared__ int wsum[4];
    const int t = threadIdx.x, lane = t & 63, wid = t >> 6;
    const int i = blockIdx.x * 256 + t;
    int v = (i < n) ? deg[i] : 0;
    int x = v;
    #pragma unroll
    for (int d = 1; d < 64; d <<= 1) { int y = __shfl_up(x, d, 64); if (lane >= d) x += y; }
    if (lane == 63) wsum[wid] = x;
    __syncthreads();
    if (wid == 0 && lane < 4) {
        int ws = wsum[lane], xs = ws;
        #pragma unroll
        for (int d = 1; d < 4; d <<= 1) { int y = __shfl_up(xs, d, 64); if (lane >= d) xs += y; }
        wsum[lane] = xs - ws;
    }
    __syncthreads();
    int excl = wsum[wid] + (x - v);
    if (i < n) {
        rowptr[i] = excl;
        invdeg[i] = 1.0f / (float)((v > 1) ? v : 1);
    }
    if (t == 255) bsum[blockIdx.x] = excl + v;
}

// Phase 2: exclusive scan of bsum[nb] in place (nb <= 256), one block.
__global__ __launch_bounds__(256) void scan_p2(int* __restrict__ bsum, int nb) {
    __shared__ int wsum[4];
    const int t = threadIdx.x, lane = t & 63, wid = t >> 6;
    int v = (t < nb) ? bsum[t] : 0;
    int x = v;
    #pragma unroll
    for (int d = 1; d < 64; d <<= 1) { int y = __shfl_up(x, d, 64); if (lane >= d) x += y; }
    if (lane == 63) wsum[wid] = x;
    __syncthreads();
    if (wid == 0 && lane < 4) {
        int ws = wsum[lane], xs = ws;
        #pragma unroll
        for (int d = 1; d < 4; d <<= 1) { int y = __shfl_up(xs, d, 64); if (lane >= d) xs += y; }
        wsum[lane] = xs - ws;
    }
    __syncthreads();
    if (t < nb) bsum[t] = wsum[wid] + (x - v);
}

// Phase 3: add block offsets; ALSO initialize cursor = rowptr so fill needs
// only one random access per edge (atomic returns the absolute slot).
__global__ __launch_bounds__(256) void scan_p3(int* __restrict__ rowptr,
                                               int* __restrict__ cursor,
                                               const int* __restrict__ bsum,
                                               int n, int E) {
    int i = blockIdx.x * 256 + threadIdx.x;
    if (i < n) {
        int v = rowptr[i] + bsum[blockIdx.x];
        rowptr[i] = v;
        cursor[i] = v;
    }
    if (i == 0) rowptr[n] = E;
}

__global__ __launch_bounds__(256) void fill_kernel(const int* __restrict__ ei,
                                                   int* __restrict__ cursor,
                                                   int* __restrict__ colidx, int E) {
    int e = blockIdx.x * blockDim.x + threadIdx.x;
    if (e < E) {
        int src = ei[e];
        int dst = ei[E + e];
        int pos = atomicAdd(&cursor[dst], 1);   // absolute slot (cursor=rowptr)
        colidx[pos] = src;
    }
}

// ---------------------------------------------------------------------------
// Aggregation: wave-per-node mean, 2-deep software pipeline. Lane = (s =
// neighbor slot 0..3, c4 = f4 chunk 0..15). At node i we issue rowptr/invdeg
// for i+2 and the first colidx chunk for i+1 (its rowptr landed last iter),
// so only the gather latency of the current node is exposed. All __shfl
// executed by ALL lanes (R3 lesson: bpermute from inactive lanes = garbage).
// ---------------------------------------------------------------------------

__global__ __launch_bounds__(256) void aggregate_kernel(
    const float* __restrict__ h_in, float* __restrict__ mean_out,
    const int* __restrict__ rowptr, const int* __restrict__ colidx,
    const float* __restrict__ inv_deg, int n) {
    const int lane = threadIdx.x & 63;
    const int wslot = __builtin_amdgcn_readfirstlane(threadIdx.x >> 6);
    const int s = lane >> 4;
    const int c4 = lane & 15;
    const float4* __restrict__ h4 = (const float4*)h_in;
    float4* __restrict__ m4 = (float4*)mean_out;

    const int wave = blockIdx.x * 4 + wslot;
    const int nwaves = gridDim.x * 4;

    int node = wave;
    if (node >= n) return;

    // Pipeline prologue: bounds for node and node+nwaves; first chunk for node.
    int beg = rowptr[node];
    int end = rowptr[node + 1];
    float idg = inv_deg[node];
    int nn1 = node + nwaves;
    int beg1 = 0, end1 = 0; float idg1 = 0.f;
    if (nn1 < n) { beg1 = rowptr[nn1]; end1 = rowptr[nn1 + 1]; idg1 = inv_deg[nn1]; }
    {
        int m0 = end - beg; if (m0 > 64) m0 = 64;
        // fallthrough load below uses this bound
        beg = beg;  // keep
    }
    int m_cur = end - beg; if (m_cur > 64) m_cur = 64;
    int ci = (lane < m_cur) ? colidx[beg + lane] : 0;

    while (true) {
        // Prefetch bounds two ahead, colidx chunk one ahead.
        const int nn2 = node + 2 * nwaves;
        int beg2 = 0, end2 = 0; float idg2 = 0.f;
        if (nn2 < n) { beg2 = rowptr[nn2]; end2 = rowptr[nn2 + 1]; idg2 = inv_deg[nn2]; }
        int nci = 0;
        int m1 = end1 - beg1; if (m1 > 64) m1 = 64;
        if (nn1 < n && lane < m1) nci = colidx[beg1 + lane];

        // ---- gather current node ----
        float4 a = {0.f, 0.f, 0.f, 0.f};
        const int m = m_cur;
        const int full = m >> 2;
        #pragma unroll 4
        for (int t = 0; t < full; ++t) {
            int idx = __shfl(ci, 4 * t + s, 64);   // all lanes active
            float4 v = h4[(size_t)idx * 16 + c4];
            a.x += v.x; a.y += v.y; a.z += v.z; a.w += v.w;
        }
        {
            const int rem = m & 3;
            int idxr = __shfl(ci, (4 * full + s) & 63, 64);  // outside branch
            if (s < rem) {
                float4 v = h4[(size_t)idxr * 16 + c4];
                a.x += v.x; a.y += v.y; a.z += v.z; a.w += v.w;
            }
        }
        // rare: degree > 64
        if (end - beg > 64) {
            for (int k = beg + 64; k < end; k += 64) {
                int mm = end - k; if (mm > 64) mm = 64;
                int cc = 0;
                if (lane < mm) cc = colidx[k + lane];
                const int f2 = mm >> 2;
                for (int t = 0; t < f2; ++t) {
                    int idx = __shfl(cc, 4 * t + s, 64);
                    float4 v = h4[(size_t)idx * 16 + c4];
                    a.x += v.x; a.y += v.y; a.z += v.z; a.w += v.w;
                }
                const int rem = mm & 3;
                int idxr = __shfl(cc, (4 * f2 + s) & 63, 64);
                if (s < rem) {
                    float4 v = h4[(size_t)idxr * 16 + c4];
                    a.x += v.x; a.y += v.y; a.z += v.z; a.w += v.w;
                }
            }
        }

        // reduce 4 neighbor slots (lane bits 4,5)
        #pragma unroll
        for (int d = 16; d <= 32; d <<= 1) {
            a.x += __shfl_xor(a.x, d, 64);
            a.y += __shfl_xor(a.y, d, 64);
            a.z += __shfl_xor(a.z, d, 64);
            a.w += __shfl_xor(a.w, d, 64);
        }
        if (s == 0) {
            float4 mm2 = {a.x * idg, a.y * idg, a.z * idg, a.w * idg};
            m4[(size_t)node * 16 + c4] = mm2;
        }

        // rotate pipeline
        node = nn1;
        if (node >= n) break;
        beg = beg1; end = end1; idg = idg1; ci = nci;
        m_cur = end - beg; if (m_cur > 64) m_cur = 64;
        nn1 = nn2; beg1 = beg2; end1 = end2; idg1 = idg2;
    }
}

// ---------------------------------------------------------------------------
// Dense: out = leaky(mean @ Wl + bl + self @ Wr), 64x64 tile per block,
// 4x4 register blocking per thread (rows r0+16s, cols j0..j0+3). All frags
// constant-indexed float4 -> registers, no spill.
// ---------------------------------------------------------------------------

#define FMA4(acc, am, b0, b1, b2, b3)                                  \
    acc.x += am.x * b0.x + am.y * b1.x + am.z * b2.x + am.w * b3.x;    \
    acc.y += am.x * b0.y + am.y * b1.y + am.z * b2.y + am.w * b3.y;    \
    acc.z += am.x * b0.z + am.y * b1.z + am.z * b2.z + am.w * b3.z;    \
    acc.w += am.x * b0.w + am.y * b1.w + am.z * b2.w + am.w * b3.w;

#define GEMM_BODY(EXTRA_SHARED)                                             \
    __shared__ float sA[64 * 68];                                           \
    __shared__ float sS[64 * 68];                                           \
    __shared__ float sWl[64 * 64];                                          \
    __shared__ float sWr[64 * 64];                                          \
    EXTRA_SHARED                                                            \
    const int t = threadIdx.x;                                              \
    const int r0 = t & 15;                                                  \
    const int j0 = (t >> 4) * 4;                                            \
    const int base = blockIdx.x * 64;                                       \
    const int rows = min(64, n - base);                                     \
    const float4* __restrict__ m4 = (const float4*)mean;                    \
    const float4* __restrict__ h4 = (const float4*)h_in;                    \
    _Pragma("unroll")                                                       \
    for (int idx = 0; idx < 4; ++idx) {                                     \
        int i = t + idx * 256;                                              \
        ((float4*)sWl)[i] = ((const float4*)Wl)[i];                         \
        ((float4*)sWr)[i] = ((const float4*)Wr)[i];                         \
    }                                                                       \
    _Pragma("unroll")                                                       \
    for (int idx = 0; idx < 4; ++idx) {                                     \
        int i = t + idx * 256;                                              \
        int r = i >> 4, c4 = i & 15;                                        \
        float4 va = {0.f, 0.f, 0.f, 0.f}, vs = {0.f, 0.f, 0.f, 0.f};        \
        if (r < rows) {                                                     \
            va = m4[(size_t)(base + r) * 16 + c4];                          \
            vs = h4[(size_t)(base + r) * 16 + c4];                          \
        }                                                                   \
        *(float4*)(sA + r * 68 + 4 * c4) = va;                              \
        *(float4*)(sS + r * 68 + 4 * c4) = vs;                              \
    }                                                                       \
    __syncthreads();                                                        \
    const float4 bias = *(const float4*)(bl + j0);                          \
    float4 acc0 = bias, acc1 = bias, acc2 = bias, acc3 = bias;              \
    _Pragma("unroll 2")                                                     \
    for (int k4 = 0; k4 < 16; ++k4) {                                       \
        float4 b0 = *(const float4*)(sWl + (4 * k4 + 0) * 64 + j0);         \
        float4 b1 = *(const float4*)(sWl + (4 * k4 + 1) * 64 + j0);         \
        float4 b2 = *(const float4*)(sWl + (4 * k4 + 2) * 64 + j0);         \
        float4 b3 = *(const float4*)(sWl + (4 * k4 + 3) * 64 + j0);         \
        float4 a0 = *(const float4*)(sA + (r0 +  0) * 68 + 4 * k4);         \
        float4 a1 = *(const float4*)(sA + (r0 + 16) * 68 + 4 * k4);         \
        float4 a2 = *(const float4*)(sA + (r0 + 32) * 68 + 4 * k4);         \
        float4 a3 = *(const float4*)(sA + (r0 + 48) * 68 + 4 * k4);         \
        FMA4(acc0, a0, b0, b1, b2, b3)                                      \
        FMA4(acc1, a1, b0, b1, b2, b3)                                      \
        FMA4(acc2, a2, b0, b1, b2, b3)                                      \
        FMA4(acc3, a3, b0, b1, b2, b3)                                      \
        b0 = *(const float4*)(sWr + (4 * k4 + 0) * 64 + j0);                \
        b1 = *(const float4*)(sWr + (4 * k4 + 1) * 64 + j0);                \
        b2 = *(const float4*)(sWr + (4 * k4 + 2) * 64 + j0);                \
        b3 = *(const float4*)(sWr + (4 * k4 + 3) * 64 + j0);                \
        a0 = *(const float4*)(sS + (r0 +  0) * 68 + 4 * k4);                \
        a1 = *(const float4*)(sS + (r0 + 16) * 68 + 4 * k4);                \
        a2 = *(const float4*)(sS + (r0 + 32) * 68 + 4 * k4);                \
        a3 = *(const float4*)(sS + (r0 + 48) * 68 + 4 * k4);                \
        FMA4(acc0, a0, b0, b1, b2, b3)                                      \
        FMA4(acc1, a1, b0, b1, b2, b3)                                      \
        FMA4(acc2, a2, b0, b1, b2, b3)                                      \
        FMA4(acc3, a3, b0, b1, b2, b3)                                      \
    }                                                                       \
    acc0.x = (acc0.x > 0.f) ? acc0.x : SLOPE * acc0.x;                      \
    acc0.y = (acc0.y > 0.f) ? acc0.y : SLOPE * acc0.y;                      \
    acc0.z = (acc0.z > 0.f) ? acc0.z : SLOPE * acc0.z;                      \
    acc0.w = (acc0.w > 0.f) ? acc0.w : SLOPE * acc0.w;                      \
    acc1.x = (acc1.x > 0.f) ? acc1.x : SLOPE * acc1.x;                      \
    acc1.y = (acc1.y > 0.f) ? acc1.y : SLOPE * acc1.y;                      \
    acc1.z = (acc1.z > 0.f) ? acc1.z : SLOPE * acc1.z;                      \
    acc1.w = (acc1.w > 0.f) ? acc1.w : SLOPE * acc1.w;                      \
    acc2.x = (acc2.x > 0.f) ? acc2.x : SLOPE * acc2.x;                      \
    acc2.y = (acc2.y > 0.f) ? acc2.y : SLOPE * acc2.y;                      \
    acc2.z = (acc2.z > 0.f) ? acc2.z : SLOPE * acc2.z;                      \
    acc2.w = (acc2.w > 0.f) ? acc2.w : SLOPE * acc2.w;                      \
    acc3.x = (acc3.x > 0.f) ? acc3.x : SLOPE * acc3.x;                      \
    acc3.y = (acc3.y > 0.f) ? acc3.y : SLOPE * acc3.y;                      \
    acc3.z = (acc3.z > 0.f) ? acc3.z : SLOPE * acc3.z;                      \
    acc3.w = (acc3.w > 0.f) ? acc3.w : SLOPE * acc3.w;

__global__ __launch_bounds__(256, 2) void sage_gemm(
    const float* __restrict__ mean, const float* __restrict__ h_in,
    float* __restrict__ h_out,
    const float* __restrict__ Wl, const float* __restrict__ bl,
    const float* __restrict__ Wr, int n) {
    GEMM_BODY()
    #define STORE_ROW(S, ACC)                                               \
        { int r = r0 + 16 * S;                                              \
          if (r < rows)                                                     \
              *(float4*)(h_out + (size_t)(base + r) * HD + j0) = ACC; }
    STORE_ROW(0, acc0)
    STORE_ROW(1, acc1)
    STORE_ROW(2, acc2)
    STORE_ROW(3, acc3)
    #undef STORE_ROW
}

// Layer-3 variant: h3 never hits memory — dot with Wout, cross-wave LDS
// reduction, write out[node] directly.
__global__ __launch_bounds__(256, 2) void sage_gemm_out(
    const float* __restrict__ mean, const float* __restrict__ h_in,
    const float* __restrict__ Wl, const float* __restrict__ bl,
    const float* __restrict__ Wr,
    const float* __restrict__ Wout, const float* __restrict__ bout,
    float* __restrict__ out, int n) {
    GEMM_BODY(__shared__ float s_part[16][64];)
    const float4 w4 = *(const float4*)(Wout + j0);
    const int jg = t >> 4;
    s_part[jg][r0 +  0] = acc0.x * w4.x + acc0.y * w4.y + acc0.z * w4.z + acc0.w * w4.w;
    s_part[jg][r0 + 16] = acc1.x * w4.x + acc1.y * w4.y + acc1.z * w4.z + acc1.w * w4.w;
    s_part[jg][r0 + 32] = acc2.x * w4.x + acc2.y * w4.y + acc2.z * w4.z + acc2.w * w4.w;
    s_part[jg][r0 + 48] = acc3.x * w4.x + acc3.y * w4.y + acc3.z * w4.z + acc3.w * w4.w;
    __syncthreads();
    if (t < 64) {
        float sum = 0.f;
        #pragma unroll
        for (int g = 0; g < 16; ++g) sum += s_part[g][t];
        if (t < rows) out[base + t] = sum + bout[0];
    }
}

// ---------------------------------------------------------------------------

extern "C" void kernel_launch(void* const* d_in, const int* in_sizes, int n_in,
                              void* d_out, int out_size, void* d_ws, size_t ws_size,
                              hipStream_t stream) {
    const float* x   = (const float*)d_in[0];
    const int* ei    = (const int*)d_in[1];
    const float* Wl1 = (const float*)d_in[2];
    const float* bl1 = (const float*)d_in[3];
    const float* Wr1 = (const float*)d_in[4];
    const float* Wl2 = (const float*)d_in[5];
    const float* bl2 = (const float*)d_in[6];
    const float* Wr2 = (const float*)d_in[7];
    const float* Wl3 = (const float*)d_in[8];
    const float* bl3 = (const float*)d_in[9];
    const float* Wr3 = (const float*)d_in[10];
    const float* Wout = (const float*)d_in[11];
    const float* bout = (const float*)d_in[12];
    float* out = (float*)d_out;

    const int N = in_sizes[0] / HD;       // 50000
    const int E = in_sizes[1] / 2;        // 800000

    // Workspace layout — float4-accessed buffers first (16B alignment).
    float* hMean  = (float*)d_ws;                   // [N*64]
    float* hA     = hMean + (size_t)N * HD;         // [N*64]
    float* hB     = hA + (size_t)N * HD;            // [N*64]
    int* deg      = (int*)(hB + (size_t)N * HD);    // [N]
    int* cursor   = deg + N;                        // [N]
    int* rowptr   = cursor + N;                     // [N+1]
    float* invdeg = (float*)(rowptr + N + 1);       // [N]
    int* colidx   = (int*)(invdeg + N);             // [E]
    int* bsum     = colidx + E;                     // [<=256]

    hipMemsetAsync(deg, 0, (size_t)N * sizeof(int), stream);

    const int eb = (E + 255) / 256;
    const int nb = (N + 255) / 256;       // 196 <= 256
    count_kernel<<<eb, 256, 0, stream>>>(ei, deg, E);
    scan_p1<<<nb, 256, 0, stream>>>(deg, rowptr, invdeg, bsum, N);
    scan_p2<<<1, 256, 0, stream>>>(bsum, nb);
    scan_p3<<<nb, 256, 0, stream>>>(rowptr, cursor, bsum, N, E);
    fill_kernel<<<eb, 256, 0, stream>>>(ei, cursor, colidx, E);

    const int agrid = 2048;               // 8192 waves, grid-stride
    const int ggrid = (N + 63) / 64;      // 782 tiles

    aggregate_kernel<<<agrid, 256, 0, stream>>>(x, hMean, rowptr, colidx, invdeg, N);
    sage_gemm<<<ggrid, 256, 0, stream>>>(hMean, x, hA, Wl1, bl1, Wr1, N);

    aggregate_kernel<<<agrid, 256, 0, stream>>>(hA, hMean, rowptr, colidx, invdeg, N);
    sage_gemm<<<ggrid, 256, 0, stream>>>(hMean, hA, hB, Wl2, bl2, Wr2, N);

    aggregate_kernel<<<agrid, 256, 0, stream>>>(hB, hMean, rowptr, colidx, invdeg, N);
    sage_gemm_out<<<ggrid, 256, 0, stream>>>(hMean, hB, Wl3, bl3, Wr3, Wout, bout, out, N);
}